// Round 8
// baseline (212.392 us; speedup 1.0000x reference)
//
#include <hip/hip_runtime.h>

typedef __attribute__((ext_vector_type(8))) short short8;
typedef __attribute__((ext_vector_type(4))) float f32x4;
typedef __attribute__((ext_vector_type(4))) unsigned short ushort4v;

struct DB0 { static constexpr int value = 0; };
struct DB1 { static constexpr int value = 1; };

__device__ __forceinline__ unsigned short f2bf(float f) {
  unsigned int u = __float_as_uint(f);
  u += 0x7fffu + ((u >> 16) & 1u);
  return (unsigned short)(u >> 16);
}
__device__ __forceinline__ float bf2f(unsigned short h) {
  return __uint_as_float(((unsigned int)h) << 16);
}

__device__ __forceinline__ void gload16(const unsigned short* g, unsigned short* l) {
  __builtin_amdgcn_global_load_lds(
      (const __attribute__((address_space(1))) unsigned int*)g,
      (__attribute__((address_space(3))) unsigned int*)l,
      16, 0, 0);
}

template <int OFF>
__device__ __forceinline__ short8 dsr(unsigned a) {
  short8 r;
  asm volatile("ds_read_b128 %0, %1 offset:%2" : "=v"(r) : "v"(a), "n"(OFF));
  return r;
}

__device__ __forceinline__ void bar() {
  asm volatile("" ::: "memory");
  __builtin_amdgcn_s_barrier();
  asm volatile("" ::: "memory");
}

// ---------------- convert x (f32) -> bf16 ----------------
__global__ __launch_bounds__(256) void conv_x_kernel(const float* __restrict__ x,
                                                     unsigned short* __restrict__ xb) {
  int i = blockIdx.x * 256 + threadIdx.x;
  f32x4 v = ((const f32x4*)x)[i];
  ushort4v o;
  o[0] = f2bf(v[0]); o[1] = f2bf(v[1]); o[2] = f2bf(v[2]); o[3] = f2bf(v[3]);
  ((ushort4v*)xb)[i] = o;
}

// ------------- transpose+convert W: f32 [K][N] -> bf16 [N][K] -------------
__global__ __launch_bounds__(256) void transpose_w_kernel(const float* __restrict__ W,
                                                          unsigned short* __restrict__ Wt,
                                                          int K, int N) {
  __shared__ float tile[32][33];
  int n0 = blockIdx.x * 32, k0 = blockIdx.y * 32;
  int tx = threadIdx.x, ty = threadIdx.y;
#pragma unroll
  for (int j = 0; j < 32; j += 8)
    tile[ty + j][tx] = W[(size_t)(k0 + ty + j) * N + n0 + tx];
  __syncthreads();
#pragma unroll
  for (int j = 0; j < 32; j += 8)
    Wt[(size_t)(n0 + ty + j) * K + k0 + tx] = f2bf(tile[tx][ty + j]);
}

// ------- transpose V (bf16 part of qkv) -> vt [B][1024][2048] -------
__global__ __launch_bounds__(256) void transpose_v_kernel(const unsigned short* __restrict__ qkv,
                                                          unsigned short* __restrict__ vt) {
  __shared__ unsigned short tile[32][33];
  int b = blockIdx.z;
  int key0 = blockIdx.x * 32, d0 = blockIdx.y * 32;
  int tx = threadIdx.x, ty = threadIdx.y;
#pragma unroll
  for (int j = 0; j < 32; j += 8)
    tile[ty + j][tx] = qkv[(size_t)(b * 2048 + key0 + ty + j) * 3072 + 2048 + d0 + tx];
  __syncthreads();
#pragma unroll
  for (int j = 0; j < 32; j += 8)
    vt[(size_t)(b * 1024 + d0 + ty + j) * 2048 + key0 + tx] = tile[tx][ty + j];
}

// ------- row softmax on S (bf16, in place), causal-variable length -------
__global__ __launch_bounds__(256) void softmax_kernel(unsigned short* __restrict__ S) {
  int row = blockIdx.x * 4 + (threadIdx.x >> 6);
  int l = threadIdx.x & 63;
  int rl = row & 2047;
  int rend = ((rl >> 7) + 1) << 7;
  unsigned short* p = S + (size_t)row * 2048;
  float v[32];
  float mx = -3e38f;
#pragma unroll
  for (int i = 0; i < 4; i++) {
    int c0 = (i * 64 + l) * 8;
    if (c0 < rend) {
      short8 raw = *(const short8*)&p[c0];
#pragma unroll
      for (int j = 0; j < 8; j++) {
        v[i * 8 + j] = bf2f((unsigned short)raw[j]);
        mx = fmaxf(mx, v[i * 8 + j]);
      }
    } else {
#pragma unroll
      for (int j = 0; j < 8; j++) v[i * 8 + j] = -3e38f;
    }
  }
#pragma unroll
  for (int off = 1; off < 64; off <<= 1) mx = fmaxf(mx, __shfl_xor(mx, off));
  float s = 0.f;
#pragma unroll
  for (int i = 0; i < 32; i++) { v[i] = exp2f((v[i] - mx) * 1.44269504f); s += v[i]; }
#pragma unroll
  for (int off = 1; off < 64; off <<= 1) s += __shfl_xor(s, off);
  float inv = 1.f / s;
#pragma unroll
  for (int i = 0; i < 4; i++) {
    int c0 = (i * 64 + l) * 8;
    if (c0 < rend) {
      short8 o;
#pragma unroll
      for (int j = 0; j < 8; j++) o[j] = (short)f2bf(v[i * 8 + j] * inv);
      *(short8*)&p[c0] = o;
    }
  }
}

// ======== 128x128 GEMM, BK=64 (128B LDS rows), depth-2 ring, 4 waves ======
// Full st_16x32 swizzle (conflict-free, verified r7): phys col byte =
// logical ^ ((row&7)<<4); source pre-swizzled (involution) so gload_lds
// dest stays linear. Natural dispatch order (no XCD remap — r7 showed it
// hurts L2 locality here).
// causal: 0 none; 1 mask; 2 PV K-trunc; 3 triangular grid (S);
//         4 PV K-trunc + balanced remap (pairs by0 with gy-1-by0).
template <int OUTBF>
__global__ __launch_bounds__(256) void gemm128_kernel(
    const unsigned short* __restrict__ A, int lda, long long saz,
    const unsigned short* __restrict__ Bt, int ldb, long long sbz,
    void* __restrict__ Cv, int ldc, long long scz,
    const float* __restrict__ bias, int K, float scale, int causal) {
  __shared__ __align__(16) unsigned short lds[2][16384];

  int bx, by, z;
  if (causal == 3) {
    int i = blockIdx.x;
    by = (int)((sqrtf(8.f * i + 1.f) - 1.f) * 0.5f);
    while ((by + 1) * (by + 2) / 2 <= i) by++;
    while (by * (by + 1) / 2 > i) by--;
    bx = i - by * (by + 1) / 2;
    z = blockIdx.y;
  } else if (causal == 4) {
    // balanced: co-resident slot pairs (id, id+total/2) get by0, gy-1-by0
    int gx = gridDim.x, gy = gridDim.y, gz = gridDim.z;
    int total = gx * gy * gz;
    int id = blockIdx.x + blockIdx.y * gx + blockIdx.z * gx * gy;
    int halfn = total >> 1;
    int half = id >= halfn;
    int r = id - half * halfn;
    bx = r % gx;
    int rest = r / gx;
    int by0 = rest % gy;
    z = rest / gy + half * (gz >> 1);
    by = half ? (gy - 1 - by0) : by0;
  } else {
    bx = blockIdx.x; by = blockIdx.y; z = blockIdx.z;
  }
  const int m0 = by * 128, n0 = bx * 128;
  A += (size_t)z * saz;
  Bt += (size_t)z * sbz;

  const int t = threadIdx.x;
  const int lane = t & 63, wid = t >> 6;
  const int g = lane >> 4, q = lane & 15;
  const int wm = wid >> 1, wn = wid & 1;  // wave tile 64x64

  int NT = K >> 6;
  if (causal == 1) { if (n0 >= m0 + 128) NT = 0; }
  else if (causal == 2 || causal == 4) { NT = min(K, m0 + 128) >> 6; }

  f32x4 acc[4][4] = {};

  if (NT > 0) {
    // staging: thread t writes 16B linearly at row=(t>>3), chunk=(t&7);
    // source col pre-swizzled (shorts): (t&7)*8 ^ (((t>>3)&7)<<3)
    const int scol = ((t & 7) * 8) ^ (((t >> 3) & 7) << 3);
    const unsigned short* aS = A + (size_t)(m0 + (t >> 3)) * lda + scol;
    const unsigned short* bS = Bt + (size_t)(n0 + (t >> 3)) * ldb + scol;

    auto stage = [&](int tt) {
      unsigned short* d = &lds[tt & 1][wid * 512];
      const unsigned short* sa = aS + (size_t)tt * 64;
      const unsigned short* sb = bS + (size_t)tt * 64;
      gload16(sa, d);
      gload16(sa + (size_t)32 * lda, d + 2048);
      gload16(sa + (size_t)64 * lda, d + 4096);
      gload16(sa + (size_t)96 * lda, d + 6144);
      gload16(sb, d + 8192);
      gload16(sb + (size_t)32 * ldb, d + 10240);
      gload16(sb + (size_t)64 * ldb, d + 12288);
      gload16(sb + (size_t)96 * ldb, d + 14336);
    };

    // fragment read addresses (bytes); swizzle W = (q&7)<<4
    const unsigned base =
        (unsigned)(unsigned long long)(__attribute__((address_space(3))) unsigned short*)&lds[0][0];
    const int W = (q & 7) << 4;
    const int colA0 = (g * 16) ^ W;
    const int colA1 = colA0 ^ 64;
    const unsigned aa0B = base + (unsigned)((wm * 64 + q) * 128 + colA0);
    const unsigned aa1B = base + (unsigned)((wm * 64 + q) * 128 + colA1);
    const unsigned bb0B = base + 16384u + (unsigned)((wn * 64 + q) * 128 + colA0);
    const unsigned bb1B = base + 16384u + (unsigned)((wn * 64 + q) * 128 + colA1);

    stage(0);
    asm volatile("s_waitcnt vmcnt(0)" ::: "memory");
    bar();

    auto body = [&](auto dbc, int tt) {
      constexpr int DB = decltype(dbc)::value;
      const unsigned aa0 = aa0B + DB * 32768u, aa1 = aa1B + DB * 32768u;
      const unsigned bb0 = bb0B + DB * 32768u, bb1 = bb1B + DB * 32768u;
      if (tt + 1 < NT) stage(tt + 1);
      short8 aq[4][2], bq[4][2];
      aq[0][0] = dsr<0>(aa0);    aq[0][1] = dsr<0>(aa1);
      aq[1][0] = dsr<2048>(aa0); aq[1][1] = dsr<2048>(aa1);
      aq[2][0] = dsr<4096>(aa0); aq[2][1] = dsr<4096>(aa1);
      aq[3][0] = dsr<6144>(aa0); aq[3][1] = dsr<6144>(aa1);
      bq[0][0] = dsr<0>(bb0);    bq[0][1] = dsr<0>(bb1);
      bq[1][0] = dsr<2048>(bb0); bq[1][1] = dsr<2048>(bb1);
      bq[2][0] = dsr<4096>(bb0); bq[2][1] = dsr<4096>(bb1);
      bq[3][0] = dsr<6144>(bb0); bq[3][1] = dsr<6144>(bb1);
      asm volatile("s_waitcnt lgkmcnt(0)" ::: "memory");
      __builtin_amdgcn_sched_barrier(0);
      __builtin_amdgcn_s_setprio(1);
#pragma unroll
      for (int ks = 0; ks < 2; ks++)
#pragma unroll
        for (int m = 0; m < 4; m++)
#pragma unroll
          for (int n = 0; n < 4; n++)
            acc[m][n] = __builtin_amdgcn_mfma_f32_16x16x32_bf16(aq[m][ks], bq[n][ks], acc[m][n], 0, 0, 0);
      __builtin_amdgcn_s_setprio(0);
      __builtin_amdgcn_sched_barrier(0);
      asm volatile("s_waitcnt vmcnt(0)" ::: "memory");
      bar();
    };

    int tt = 0;
    for (; tt + 2 <= NT; tt += 2) {
      body(DB0{}, tt);
      body(DB1{}, tt + 1);
    }
    if (tt < NT) body(DB0{}, tt);
  }

  // ---- epilogue ----
  const bool maskC = (causal == 1) || (causal == 3);
#pragma unroll
  for (int n = 0; n < 4; n++) {
    int colg = n0 + wn * 64 + n * 16 + q;
    float bv = bias ? bias[colg] : 0.f;
#pragma unroll
    for (int m = 0; m < 4; m++) {
      int rowb = m0 + wm * 64 + m * 16 + g * 4;
#pragma unroll
      for (int r = 0; r < 4; r++) {
        float val = acc[m][n][r] * scale + bv;
        if (maskC && colg > rowb + r) val = -1e30f;
        if (OUTBF) {
          ((unsigned short*)Cv)[(size_t)z * scz + (size_t)(rowb + r) * ldc + colg] = f2bf(val);
        } else {
          ((float*)Cv)[(size_t)z * scz + (size_t)(rowb + r) * ldc + colg] = val;
        }
      }
    }
  }
}

extern "C" void kernel_launch(void* const* d_in, const int* in_sizes, int n_in,
                              void* d_out, int out_size, void* d_ws, size_t ws_size,
                              hipStream_t stream) {
  const float* x  = (const float*)d_in[0];
  const float* Wa = (const float*)d_in[1];
  const float* ba = (const float*)d_in[2];
  const float* Wp = (const float*)d_in[3];
  const float* bp = (const float*)d_in[4];
  float* out = (float*)d_out;

  char* ws = (char*)d_ws;
  unsigned short* qkv = (unsigned short*)(ws);                 // 50331648
  unsigned short* xb  = (unsigned short*)(ws + 50331648);      // 16777216
  unsigned short* vt  = (unsigned short*)(ws + 50331648);      // overlay xb
  unsigned short* wta = (unsigned short*)(ws + 67108864);      // 6291456
  unsigned short* S   = (unsigned short*)(ws + 73400320);      // 33554432
  unsigned short* y   = (unsigned short*)(ws + 106954752);     // 16777216
  unsigned short* wtp = (unsigned short*)(ws + 123731968);     // 2097152

  conv_x_kernel<<<8192, 256, 0, stream>>>(x, xb);
  transpose_w_kernel<<<dim3(96, 32), dim3(32, 8), 0, stream>>>(Wa, wta, 1024, 3072);
  transpose_w_kernel<<<dim3(32, 32), dim3(32, 8), 0, stream>>>(Wp, wtp, 1024, 1024);

  // qkv = x @ W_attn + b_attn   [8192 x 3072]
  gemm128_kernel<1><<<dim3(24, 64, 1), 256, 0, stream>>>(
      xb, 1024, 0, wta, 1024, 0, qkv, 3072, 0, ba, 1024, 1.0f, 0);

  // S = Q @ K^T * 0.125, lower-triangle blocks only (136 per batch)
  gemm128_kernel<1><<<dim3(136, 4), 256, 0, stream>>>(
      qkv, 3072, 2048LL * 3072, qkv + 1024, 3072, 2048LL * 3072,
      S, 2048, 2048LL * 2048, nullptr, 1024, 0.125f, 3);

  softmax_kernel<<<2048, 256, 0, stream>>>(S);

  transpose_v_kernel<<<dim3(64, 32, 4), dim3(32, 8), 0, stream>>>(qkv, vt);

  // y = P @ V, per batch [2048 x 1024], K truncated, balanced remap
  gemm128_kernel<1><<<dim3(8, 16, 4), 256, 0, stream>>>(
      S, 2048, 2048LL * 2048, vt, 2048, 1024LL * 2048,
      y, 1024, 2048LL * 1024, nullptr, 2048, 1.0f, 4);

  // out = y @ W_proj + b_proj   [8192 x 1024], fp32 out
  gemm128_kernel<0><<<dim3(8, 64, 1), 256, 0, stream>>>(
      y, 1024, 0, wtp, 1024, 0, out, 1024, 0, bp, 1024, 1.0f, 0);
}

// Round 9
// 197.755 us; speedup vs baseline: 1.0740x; 1.0740x over previous
//
#include <hip/hip_runtime.h>

typedef __attribute__((ext_vector_type(8))) short short8;
typedef __attribute__((ext_vector_type(4))) float f32x4;
typedef __attribute__((ext_vector_type(4))) unsigned short ushort4v;

struct DB0 { static constexpr int value = 0; };
struct DB1 { static constexpr int value = 1; };

__device__ __forceinline__ unsigned short f2bf(float f) {
  unsigned int u = __float_as_uint(f);
  u += 0x7fffu + ((u >> 16) & 1u);
  return (unsigned short)(u >> 16);
}
__device__ __forceinline__ float bf2f(unsigned short h) {
  return __uint_as_float(((unsigned int)h) << 16);
}

__device__ __forceinline__ void gload16(const unsigned short* g, unsigned short* l) {
  __builtin_amdgcn_global_load_lds(
      (const __attribute__((address_space(1))) unsigned int*)g,
      (__attribute__((address_space(3))) unsigned int*)l,
      16, 0, 0);
}

template <int OFF>
__device__ __forceinline__ short8 dsr(unsigned a) {
  short8 r;
  asm volatile("ds_read_b128 %0, %1 offset:%2" : "=v"(r) : "v"(a), "n"(OFF));
  return r;
}

__device__ __forceinline__ void bar() {
  asm volatile("" ::: "memory");
  __builtin_amdgcn_s_barrier();
  asm volatile("" ::: "memory");
}

// ---------------- convert x (f32) -> bf16 ----------------
__global__ __launch_bounds__(256) void conv_x_kernel(const float* __restrict__ x,
                                                     unsigned short* __restrict__ xb) {
  int i = blockIdx.x * 256 + threadIdx.x;
  f32x4 v = ((const f32x4*)x)[i];
  ushort4v o;
  o[0] = f2bf(v[0]); o[1] = f2bf(v[1]); o[2] = f2bf(v[2]); o[3] = f2bf(v[3]);
  ((ushort4v*)xb)[i] = o;
}

// ------------- transpose+convert W: f32 [K][N] -> bf16 [N][K] -------------
__global__ __launch_bounds__(256) void transpose_w_kernel(const float* __restrict__ W,
                                                          unsigned short* __restrict__ Wt,
                                                          int K, int N) {
  __shared__ float tile[32][33];
  int n0 = blockIdx.x * 32, k0 = blockIdx.y * 32;
  int tx = threadIdx.x, ty = threadIdx.y;
#pragma unroll
  for (int j = 0; j < 32; j += 8)
    tile[ty + j][tx] = W[(size_t)(k0 + ty + j) * N + n0 + tx];
  __syncthreads();
#pragma unroll
  for (int j = 0; j < 32; j += 8)
    Wt[(size_t)(n0 + ty + j) * K + k0 + tx] = f2bf(tile[tx][ty + j]);
}

// ------- row softmax on S (bf16, in place), causal-variable length -------
__global__ __launch_bounds__(256) void softmax_kernel(unsigned short* __restrict__ S) {
  int row = blockIdx.x * 4 + (threadIdx.x >> 6);
  int l = threadIdx.x & 63;
  int rl = row & 2047;
  int rend = ((rl >> 7) + 1) << 7;
  unsigned short* p = S + (size_t)row * 2048;
  float v[32];
  float mx = -3e38f;
#pragma unroll
  for (int i = 0; i < 4; i++) {
    int c0 = (i * 64 + l) * 8;
    if (c0 < rend) {
      short8 raw = *(const short8*)&p[c0];
#pragma unroll
      for (int j = 0; j < 8; j++) {
        v[i * 8 + j] = bf2f((unsigned short)raw[j]);
        mx = fmaxf(mx, v[i * 8 + j]);
      }
    } else {
#pragma unroll
      for (int j = 0; j < 8; j++) v[i * 8 + j] = -3e38f;
    }
  }
#pragma unroll
  for (int off = 1; off < 64; off <<= 1) mx = fmaxf(mx, __shfl_xor(mx, off));
  float s = 0.f;
#pragma unroll
  for (int i = 0; i < 32; i++) { v[i] = exp2f((v[i] - mx) * 1.44269504f); s += v[i]; }
#pragma unroll
  for (int off = 1; off < 64; off <<= 1) s += __shfl_xor(s, off);
  float inv = 1.f / s;
#pragma unroll
  for (int i = 0; i < 4; i++) {
    int c0 = (i * 64 + l) * 8;
    if (c0 < rend) {
      short8 o;
#pragma unroll
      for (int j = 0; j < 8; j++) o[j] = (short)f2bf(v[i * 8 + j] * inv);
      *(short8*)&p[c0] = o;
    }
  }
}

// ======== 128x128 GEMM, BK=64, depth-2 ring, 4 waves, counted vmcnt ======
// st_16x32 swizzle (conflict-free): phys col byte = logical ^ ((row&7)<<4);
// source pre-swizzled (involution) so gload_lds dest stays linear.
// Schedule: ds_read -> lgkm(0) -> bar -> stage(tt+2 into freed buf) ->
// MFMA -> vmcnt(8) -> bar.  Stage-to-use distance ~2 tiles.
// causal: 0 none (+8x8 supertile dispatch swizzle); 1 mask; 2 K-trunc;
//         3 triangular grid (S); 4 K-trunc + balanced remap (PV).
template <int OUTBF>
__global__ __launch_bounds__(256) void gemm128_kernel(
    const unsigned short* __restrict__ A, int lda, long long saz,
    const unsigned short* __restrict__ Bt, int ldb, long long sbz,
    void* __restrict__ Cv, int ldc, long long scz,
    const float* __restrict__ bias, int K, float scale, int causal) {
  __shared__ __align__(16) unsigned short lds[2][16384];

  int bx, by, z;
  if (causal == 3) {
    int i = blockIdx.x;
    by = (int)((sqrtf(8.f * i + 1.f) - 1.f) * 0.5f);
    while ((by + 1) * (by + 2) / 2 <= i) by++;
    while (by * (by + 1) / 2 > i) by--;
    bx = i - by * (by + 1) / 2;
    z = blockIdx.y;
  } else if (causal == 4) {
    // balanced: co-resident slot pairs (id, id+total/2) get by0, gy-1-by0
    int gx = gridDim.x, gy = gridDim.y, gz = gridDim.z;
    int total = gx * gy * gz;
    int id = blockIdx.x + blockIdx.y * gx + blockIdx.z * gx * gy;
    int halfn = total >> 1;
    int half = id >= halfn;
    int r = id - half * halfn;
    bx = r % gx;
    int rest = r / gx;
    int by0 = rest % gy;
    z = rest / gy + half * (gz >> 1);
    by = half ? (gy - 1 - by0) : by0;
  } else {
    bx = blockIdx.x; by = blockIdx.y; z = blockIdx.z;
    int gx = gridDim.x, gy = gridDim.y;
    if (causal == 0 && (gx & 7) == 0 && (gy & 7) == 0) {
      // 8x8 supertile: 64 consecutive ids cover a compact 8x8 region
      int id = by * gx + bx;
      int s = id >> 6, w = id & 63;
      int spx = gx >> 3;
      bx = (s % spx) * 8 + (w & 7);
      by = (s / spx) * 8 + (w >> 3);
    }
  }
  const int m0 = by * 128, n0 = bx * 128;
  A += (size_t)z * saz;
  Bt += (size_t)z * sbz;

  const int t = threadIdx.x;
  const int lane = t & 63, wid = t >> 6;
  const int g = lane >> 4, q = lane & 15;
  const int wm = wid >> 1, wn = wid & 1;  // wave tile 64x64

  int NT = K >> 6;
  if (causal == 1) { if (n0 >= m0 + 128) NT = 0; }
  else if (causal == 2 || causal == 4) { NT = min(K, m0 + 128) >> 6; }

  f32x4 acc[4][4] = {};

  if (NT > 0) {
    // staging: thread t writes 16B linearly at row=(t>>3), chunk=(t&7);
    // source col pre-swizzled (shorts): (t&7)*8 ^ (((t>>3)&7)<<3)
    const int scol = ((t & 7) * 8) ^ (((t >> 3) & 7) << 3);
    const unsigned short* aS = A + (size_t)(m0 + (t >> 3)) * lda + scol;
    const unsigned short* bS = Bt + (size_t)(n0 + (t >> 3)) * ldb + scol;

    auto stage = [&](int tt) {
      unsigned short* d = &lds[tt & 1][wid * 512];
      const unsigned short* sa = aS + (size_t)tt * 64;
      const unsigned short* sb = bS + (size_t)tt * 64;
      gload16(sa, d);
      gload16(sa + (size_t)32 * lda, d + 2048);
      gload16(sa + (size_t)64 * lda, d + 4096);
      gload16(sa + (size_t)96 * lda, d + 6144);
      gload16(sb, d + 8192);
      gload16(sb + (size_t)32 * ldb, d + 10240);
      gload16(sb + (size_t)64 * ldb, d + 12288);
      gload16(sb + (size_t)96 * ldb, d + 14336);
    };

    // fragment read addresses (bytes); swizzle W = (q&7)<<4
    const unsigned base =
        (unsigned)(unsigned long long)(__attribute__((address_space(3))) unsigned short*)&lds[0][0];
    const int W = (q & 7) << 4;
    const int colA0 = (g * 16) ^ W;
    const int colA1 = colA0 ^ 64;
    const unsigned aa0B = base + (unsigned)((wm * 64 + q) * 128 + colA0);
    const unsigned aa1B = base + (unsigned)((wm * 64 + q) * 128 + colA1);
    const unsigned bb0B = base + 16384u + (unsigned)((wn * 64 + q) * 128 + colA0);
    const unsigned bb1B = base + 16384u + (unsigned)((wn * 64 + q) * 128 + colA1);

    stage(0);
    if (NT > 1) {
      stage(1);
      asm volatile("s_waitcnt vmcnt(8)" ::: "memory");
    } else {
      asm volatile("s_waitcnt vmcnt(0)" ::: "memory");
    }
    bar();

    auto body = [&](auto dbc, int tt) {
      constexpr int DB = decltype(dbc)::value;
      const unsigned aa0 = aa0B + DB * 32768u, aa1 = aa1B + DB * 32768u;
      const unsigned bb0 = bb0B + DB * 32768u, bb1 = bb1B + DB * 32768u;
      short8 aq[4][2], bq[4][2];
      aq[0][0] = dsr<0>(aa0);    aq[0][1] = dsr<0>(aa1);
      aq[1][0] = dsr<2048>(aa0); aq[1][1] = dsr<2048>(aa1);
      aq[2][0] = dsr<4096>(aa0); aq[2][1] = dsr<4096>(aa1);
      aq[3][0] = dsr<6144>(aa0); aq[3][1] = dsr<6144>(aa1);
      bq[0][0] = dsr<0>(bb0);    bq[0][1] = dsr<0>(bb1);
      bq[1][0] = dsr<2048>(bb0); bq[1][1] = dsr<2048>(bb1);
      bq[2][0] = dsr<4096>(bb0); bq[2][1] = dsr<4096>(bb1);
      bq[3][0] = dsr<6144>(bb0); bq[3][1] = dsr<6144>(bb1);
      asm volatile("s_waitcnt lgkmcnt(0)" ::: "memory");
      __builtin_amdgcn_sched_barrier(0);
      bar();  // all waves done reading buf[DB] -> safe to overwrite
      if (tt + 2 < NT) stage(tt + 2);
      __builtin_amdgcn_s_setprio(1);
#pragma unroll
      for (int ks = 0; ks < 2; ks++)
#pragma unroll
        for (int m = 0; m < 4; m++)
#pragma unroll
          for (int n = 0; n < 4; n++)
            acc[m][n] = __builtin_amdgcn_mfma_f32_16x16x32_bf16(aq[m][ks], bq[n][ks], acc[m][n], 0, 0, 0);
      __builtin_amdgcn_s_setprio(0);
      __builtin_amdgcn_sched_barrier(0);
      if (tt + 2 < NT) {
        asm volatile("s_waitcnt vmcnt(8)" ::: "memory");  // tile tt+1 landed
      } else {
        asm volatile("s_waitcnt vmcnt(0)" ::: "memory");
      }
      bar();
    };

    int tt = 0;
    for (; tt + 2 <= NT; tt += 2) {
      body(DB0{}, tt);
      body(DB1{}, tt + 1);
    }
    if (tt < NT) body(DB0{}, tt);
  }

  // ---- epilogue ----
  const bool maskC = (causal == 1) || (causal == 3);
#pragma unroll
  for (int n = 0; n < 4; n++) {
    int colg = n0 + wn * 64 + n * 16 + q;
    float bv = bias ? bias[colg] : 0.f;
#pragma unroll
    for (int m = 0; m < 4; m++) {
      int rowb = m0 + wm * 64 + m * 16 + g * 4;
#pragma unroll
      for (int r = 0; r < 4; r++) {
        float val = acc[m][n][r] * scale + bv;
        if (maskC && colg > rowb + r) val = -1e30f;
        if (OUTBF) {
          ((unsigned short*)Cv)[(size_t)z * scz + (size_t)(rowb + r) * ldc + colg] = f2bf(val);
        } else {
          ((float*)Cv)[(size_t)z * scz + (size_t)(rowb + r) * ldc + colg] = val;
        }
      }
    }
  }
}

extern "C" void kernel_launch(void* const* d_in, const int* in_sizes, int n_in,
                              void* d_out, int out_size, void* d_ws, size_t ws_size,
                              hipStream_t stream) {
  const float* x  = (const float*)d_in[0];
  const float* Wa = (const float*)d_in[1];
  const float* ba = (const float*)d_in[2];
  const float* Wp = (const float*)d_in[3];
  const float* bp = (const float*)d_in[4];
  float* out = (float*)d_out;

  char* ws = (char*)d_ws;
  unsigned short* qkv = (unsigned short*)(ws);                 // 50331648
  unsigned short* xb  = (unsigned short*)(ws + 50331648);      // 16777216
  unsigned short* vt  = (unsigned short*)(ws + 50331648);      // V'^T, overlays xb
  unsigned short* wta = (unsigned short*)(ws + 67108864);      // 6291456
  unsigned short* S   = (unsigned short*)(ws + 73400320);      // 33554432
  unsigned short* wtp = (unsigned short*)(ws + 123731968);     // 2097152

  conv_x_kernel<<<8192, 256, 0, stream>>>(x, xb);
  transpose_w_kernel<<<dim3(96, 32), dim3(32, 8), 0, stream>>>(Wa, wta, 1024, 3072);
  transpose_w_kernel<<<dim3(32, 32), dim3(32, 8), 0, stream>>>(Wp, wtp, 1024, 1024);

  // qkv = x @ W_attn + b_attn   [8192 x 3072]
  gemm128_kernel<1><<<dim3(24, 64, 1), 256, 0, stream>>>(
      xb, 1024, 0, wta, 1024, 0, qkv, 3072, 0, ba, 1024, 1.0f, 0);

  // S = Q @ K^T * 0.125, lower-triangle blocks only (136 per batch)
  gemm128_kernel<1><<<dim3(136, 4), 256, 0, stream>>>(
      qkv, 3072, 2048LL * 3072, qkv + 1024, 3072, 2048LL * 3072,
      S, 2048, 2048LL * 2048, nullptr, 1024, 0.125f, 3);

  softmax_kernel<<<2048, 256, 0, stream>>>(S);

  // V'^T = Wp^T @ V^T : [1024 x 2048] per batch; A=wtp, Bt=V-part of qkv
  gemm128_kernel<1><<<dim3(16, 8, 4), 256, 0, stream>>>(
      wtp, 1024, 0, qkv + 2048, 3072, 2048LL * 3072,
      vt, 2048, 2048LL * 1024, nullptr, 1024, 1.0f, 0);

  // out = P @ V' + b_proj : [2048 x 1024] per batch, fp32, K-trunc balanced
  gemm128_kernel<0><<<dim3(8, 16, 4), 256, 0, stream>>>(
      S, 2048, 2048LL * 2048, vt, 2048, 2048LL * 1024,
      out, 1024, 2048LL * 1024, bp, 2048, 1.0f, 4);
}